// Round 8
// baseline (235.992 us; speedup 1.0000x reference)
//
#include <hip/hip_runtime.h>
#include <hip/hip_bf16.h>
#include <math.h>

// Problem constants
#define BATCH   2
#define SEQ     2048
#define NHEAD   16
#define HDIM    64
#define NEMBD   1024
#define C3      (3*NEMBD)
#define MROWS   (BATCH*SEQ)   // 4096

typedef short bf16x8 __attribute__((ext_vector_type(8)));
typedef float f32x4  __attribute__((ext_vector_type(4)));

static __device__ __forceinline__ short f2bf(float x) {
    union { __hip_bfloat16 h; short s; } u;
    u.h = __float2bfloat16(x);
    return u.s;
}

static __device__ __forceinline__ void stc(float* p, float v) { *p = v; }
static __device__ __forceinline__ void stc(short* p, float v) { *p = f2bf(v); }

// async global->LDS, 16B per lane. LDS dest = wave-uniform base + lane*16.
static __device__ __forceinline__ void gl_lds16(const short* g, short* lds_base) {
    __builtin_amdgcn_global_load_lds(
        (const __attribute__((address_space(1))) unsigned int*)g,
        (__attribute__((address_space(3))) unsigned int*)lds_base,
        16, 0, 0);
}

// ---------------------------------------------------------------------------
// Elementwise fp32 -> bf16 convert (8 elems/thread).
// ---------------------------------------------------------------------------
__global__ __launch_bounds__(256) void conv_x(const float* __restrict__ in,
                                              short* __restrict__ out, int n) {
    const int i = (blockIdx.x * 256 + threadIdx.x) * 8;
    if (i >= n) return;
    float4 a = *(const float4*)(in + i);
    float4 b = *(const float4*)(in + i + 4);
    bf16x8 o;
    o[0] = f2bf(a.x); o[1] = f2bf(a.y); o[2] = f2bf(a.z); o[3] = f2bf(a.w);
    o[4] = f2bf(b.x); o[5] = f2bf(b.y); o[6] = f2bf(b.z); o[7] = f2bf(b.w);
    *(bf16x8*)(out + i) = o;
}

// ---------------------------------------------------------------------------
// Weight transpose + convert: in [K,N] fp32 row-major -> out [N,K] bf16.
// ---------------------------------------------------------------------------
__global__ __launch_bounds__(256) void conv_wt(const float* __restrict__ in,
                                               short* __restrict__ out,
                                               int K, int N) {
    __shared__ short tile[64][66];
    const int kt = blockIdx.y * 64, nt = blockIdx.x * 64;
    const int r  = threadIdx.x / 4;
    const int c0 = (threadIdx.x % 4) * 16;

    const float* src = in + (size_t)(kt + r) * N + nt + c0;
#pragma unroll
    for (int c = 0; c < 16; c += 4) {
        float4 v = *(const float4*)(src + c);
        tile[r][c0 + c + 0] = f2bf(v.x);
        tile[r][c0 + c + 1] = f2bf(v.y);
        tile[r][c0 + c + 2] = f2bf(v.z);
        tile[r][c0 + c + 3] = f2bf(v.w);
    }
    __syncthreads();

    const int nr  = threadIdx.x / 4;
    const int k0c = (threadIdx.x % 4) * 16;
    bf16x8 o0, o1;
#pragma unroll
    for (int k = 0; k < 8; ++k) o0[k] = tile[k0c + k][nr];
#pragma unroll
    for (int k = 0; k < 8; ++k) o1[k] = tile[k0c + 8 + k][nr];
    short* dst = out + (size_t)(nt + nr) * K + kt + k0c;
    *(bf16x8*)dst       = o0;
    *(bf16x8*)(dst + 8) = o1;
}

// ---------------------------------------------------------------------------
// bf16 MFMA GEMM (m97 structure): C = A @ B, A [M,K], BT [N,K] bf16.
// ---------------------------------------------------------------------------
template <typename OT>
__global__ __launch_bounds__(256) void gemm_bt(const short* __restrict__ A,
                                               const short* __restrict__ BT,
                                               OT* __restrict__ C,
                                               int M, int N, int K) {
    __shared__ short As[128 * 32];
    __shared__ short Bs[128 * 32];

    const int tid  = threadIdx.x;
    const int wave = tid >> 6;
    const int lane = tid & 63;
    const int quad = lane >> 4;
    const int col  = lane & 15;
    const int m0 = blockIdx.y * 128;
    const int n0 = blockIdx.x * 128;
    const int mq = (wave >> 1) * 64;
    const int nq = (wave & 1) * 64;

    f32x4 acc[4][4] = {};

    const int cA  = wave * 64 + lane;
    const int cA1 = cA + 256;

    for (int k0 = 0; k0 < K; k0 += 32) {
        if (k0) __syncthreads();
        gl_lds16(A + (size_t)(m0 + (cA  >> 2)) * K + k0 + (cA  & 3) * 8,
                 &As[wave * 512]);
        gl_lds16(A + (size_t)(m0 + (cA1 >> 2)) * K + k0 + (cA1 & 3) * 8,
                 &As[2048 + wave * 512]);
        gl_lds16(BT + (size_t)(n0 + (cA  >> 2)) * K + k0 + (cA  & 3) * 8,
                 &Bs[wave * 512]);
        gl_lds16(BT + (size_t)(n0 + (cA1 >> 2)) * K + k0 + (cA1 & 3) * 8,
                 &Bs[2048 + wave * 512]);
        __syncthreads();

        bf16x8 af[4], bfr[4];
#pragma unroll
        for (int mt = 0; mt < 4; ++mt)
            af[mt] = *(const bf16x8*)&As[(mq + mt * 16 + col) * 32 + quad * 8];
#pragma unroll
        for (int nt = 0; nt < 4; ++nt)
            bfr[nt] = *(const bf16x8*)&Bs[(nq + nt * 16 + col) * 32 + quad * 8];
#pragma unroll
        for (int mt = 0; mt < 4; ++mt)
#pragma unroll
            for (int nt = 0; nt < 4; ++nt)
                acc[mt][nt] = __builtin_amdgcn_mfma_f32_16x16x32_bf16(
                    af[mt], bfr[nt], acc[mt][nt], 0, 0, 0);
    }

#pragma unroll
    for (int mt = 0; mt < 4; ++mt)
#pragma unroll
        for (int r = 0; r < 4; ++r) {
            const int row = m0 + mq + mt * 16 + quad * 4 + r;
            OT* cp = C + (size_t)row * N + n0 + nq + col;
#pragma unroll
            for (int nt = 0; nt < 4; ++nt)
                stc(cp + nt * 16, acc[mt][nt][r]);
        }
}

// ---------------------------------------------------------------------------
// V transpose: qkvb bf16 [B*T,3072] (v at 2048+h*64) -> vt [B*H][64][2048]
// ---------------------------------------------------------------------------
__global__ __launch_bounds__(256) void conv_vt(const short* __restrict__ qkvb,
                                               short* __restrict__ vt) {
    __shared__ short tile[64][66];
    const int b = blockIdx.z, h = blockIdx.y, t0 = blockIdx.x * 64;
    const int tt = threadIdx.x / 4;
    const int c0 = (threadIdx.x % 4) * 16;

    const short* src = qkvb + (size_t)(b * SEQ + t0 + tt) * C3 + 2 * NEMBD + h * HDIM + c0;
    bf16x8 v0 = *(const bf16x8*)src;
    bf16x8 v1 = *(const bf16x8*)(src + 8);
#pragma unroll
    for (int k = 0; k < 8; ++k) tile[tt][c0 + k]     = v0[k];
#pragma unroll
    for (int k = 0; k < 8; ++k) tile[tt][c0 + 8 + k] = v1[k];
    __syncthreads();

    const int d  = threadIdx.x / 4;
    const int tp = (threadIdx.x % 4) * 16;
    bf16x8 o0, o1;
#pragma unroll
    for (int k = 0; k < 8; ++k) o0[k] = tile[tp + k][d];
#pragma unroll
    for (int k = 0; k < 8; ++k) o1[k] = tile[tp + 8 + k][d];
    short* dst = vt + ((size_t)(b * NHEAD + h) * HDIM + d) * SEQ + t0 + tp;
    *(bf16x8*)dst       = o0;
    *(bf16x8*)(dst + 8) = o1;
}

// ---------------------------------------------------------------------------
// MFMA flash attention v5: key-dimension SPLIT (flash-decoding style).
// Fixed-max softmax p = exp2(qk*scale2 - slope2*j) has NO running max and NO
// rescaling -> partial (O,l) sums over disjoint key segments simply ADD.
// Work item = (seg, X, h, b): 64-query block X, key tiles [4*seg, 4*seg+4) of
// T = min(X+1, Tcut). ~2560 uniform (<=4-tile) items -> no makespan tail
// (R5-R7 were bound by 32 lone heavy blocks running 32 tiles serially).
// Wave-tile compute body identical to R5 (best measured). Partials merged by
// fp32 atomicAdd into Oacc/lacc (plain stores when the item covers all of T).
// ---------------------------------------------------------------------------
__global__ __launch_bounds__(256) void attn_mfma(const short* __restrict__ qkvb,
                                                 const short* __restrict__ vt,
                                                 float* __restrict__ Oacc,
                                                 float* __restrict__ lacc) {
    // [buf][region][64 rows * 32 shorts]; regions: 0=Klo 1=Khi 2=Vlo 3=Vhi
    __shared__ short KV[2][4][2048];     // 32 KB
    __shared__ short P_lds[4][16 * 64];  // 8 KB -> total 40 KB = 4 blocks/CU

    const int tid  = threadIdx.x;
    const int wave = tid >> 6;
    const int lane = tid & 63;
    const int quad = lane >> 4;
    const int col  = lane & 15;

    const int seg = blockIdx.x;
    const int X   = 31 - (int)blockIdx.y;    // mild heavy-first
    const int hb  = blockIdx.z;              // = h*2 + b
    const int h   = hb >> 1;
    const int b   = hb & 1;

    const float LOG2E  = 1.4426950408889634f;
    const float scale2 = 0.125f * LOG2E;
    const float slope2 = exp2f(-0.5f * (float)(h + 1)) * LOG2E;

    const int Tneed = X + 1;
    const int Tcut  = ((int)(56.0f / slope2) >> 6) + 1;  // ALiBi truncation
    const int T     = Tneed < Tcut ? Tneed : Tcut;
    const int t0    = seg * 4;
    if (t0 >= T) return;                     // uniform early exit, no barriers yet
    const int tend  = min(t0 + 4, T);
    const bool sole = (t0 == 0 && tend == T);  // only contributor for this slot

    const int q0 = X * 64 + wave * 16;

    const short* kb  = qkvb + (size_t)(b * SEQ) * C3 + NEMBD + h * HDIM;
    const short* vtb = vt + (size_t)(b * NHEAD + h) * HDIM * SEQ;

    // Q A-fragments: rows q0+col, dims quad*8 (+0 / +32)
    const short* qbase = qkvb + (size_t)(b * SEQ + q0 + col) * C3 + h * HDIM;
    const bf16x8 qa0 = *(const bf16x8*)(qbase + quad * 8);
    const bf16x8 qa1 = *(const bf16x8*)(qbase + 32 + quad * 8);

    f32x4 O0 = {0,0,0,0}, O1 = {0,0,0,0}, O2 = {0,0,0,0}, O3 = {0,0,0,0};
    float lsum[4] = {0.f, 0.f, 0.f, 0.f};
    short* P = P_lds[wave];

#define STAGE(t_, buf_) do {                                                   \
        const int jj = (t_) * 64;                                              \
        const int row = tid >> 2, g8 = (tid & 3) * 8;                          \
        gl_lds16(kb  + (size_t)(jj + row) * C3 + g8,      &KV[buf_][0][wave * 512]); \
        gl_lds16(kb  + (size_t)(jj + row) * C3 + 32 + g8, &KV[buf_][1][wave * 512]); \
        gl_lds16(vtb + (size_t)row * SEQ + jj + g8,       &KV[buf_][2][wave * 512]); \
        gl_lds16(vtb + (size_t)row * SEQ + jj + 32 + g8,  &KV[buf_][3][wave * 512]); \
    } while (0)

    STAGE(t0, 0);

    for (int t = t0; t < tend; ++t) {
        const int buf = (t - t0) & 1;
        __syncthreads();            // drains vmcnt -> buf ready; prev reads done
        if (t + 1 < tend) STAGE(t + 1, buf ^ 1);

        const int j0 = t * 64;

        // S = Q @ K^T from LDS K
        f32x4 S[4];
#pragma unroll
        for (int g = 0; g < 4; ++g) {
            bf16x8 k0 = *(const bf16x8*)&KV[buf][0][(g * 16 + col) * 32 + quad * 8];
            bf16x8 k1 = *(const bf16x8*)&KV[buf][1][(g * 16 + col) * 32 + quad * 8];
            f32x4 s = {0, 0, 0, 0};
            s = __builtin_amdgcn_mfma_f32_16x16x32_bf16(qa0, k0, s, 0, 0, 0);
            s = __builtin_amdgcn_mfma_f32_16x16x32_bf16(qa1, k1, s, 0, 0, 0);
            S[g] = s;
        }

        // softmax weights p = exp2(S*scale2 - slope2*j)
        const float cbase = -slope2 * (float)(j0 + col);
        const float d16   = -slope2 * 16.0f;
        float p[4][4];
        if (t == X) {               // diagonal tile: causal mask
#pragma unroll
            for (int g = 0; g < 4; ++g) {
                const float cg = cbase + d16 * (float)g;
                const int   jg = j0 + g * 16 + col;
#pragma unroll
                for (int r = 0; r < 4; ++r) {
                    const int i = q0 + quad * 4 + r;
                    p[g][r] = (jg <= i) ? exp2f(S[g][r] * scale2 + cg) : 0.f;
                }
            }
        } else {
#pragma unroll
            for (int g = 0; g < 4; ++g) {
                const float cg = cbase + d16 * (float)g;
#pragma unroll
                for (int r = 0; r < 4; ++r)
                    p[g][r] = exp2f(S[g][r] * scale2 + cg);
            }
        }
#pragma unroll
        for (int r = 0; r < 4; ++r)
            lsum[r] += (p[0][r] + p[1][r]) + (p[2][r] + p[3][r]);

        // P (C-layout) -> LDS [q][k] -> A-layout fragments
#pragma unroll
        for (int g = 0; g < 4; ++g)
#pragma unroll
            for (int r = 0; r < 4; ++r)
                P[(quad * 4 + r) * 64 + g * 16 + col] = f2bf(p[g][r]);
        __asm__ volatile("s_waitcnt lgkmcnt(0)" ::: "memory");
        bf16x8 pa0 = *(bf16x8*)&P[col * 64 + quad * 8];
        bf16x8 pa1 = *(bf16x8*)&P[col * 64 + 32 + quad * 8];
        __asm__ volatile("" ::: "memory");

        // O += P @ V: V^T B-fragments from LDS
        {
            bf16x8 vl0 = *(const bf16x8*)&KV[buf][2][(0 * 16 + col) * 32 + quad * 8];
            bf16x8 vh0 = *(const bf16x8*)&KV[buf][3][(0 * 16 + col) * 32 + quad * 8];
            O0 = __builtin_amdgcn_mfma_f32_16x16x32_bf16(pa0, vl0, O0, 0, 0, 0);
            O0 = __builtin_amdgcn_mfma_f32_16x16x32_bf16(pa1, vh0, O0, 0, 0, 0);
            bf16x8 vl1 = *(const bf16x8*)&KV[buf][2][(1 * 16 + col) * 32 + quad * 8];
            bf16x8 vh1 = *(const bf16x8*)&KV[buf][3][(1 * 16 + col) * 32 + quad * 8];
            O1 = __builtin_amdgcn_mfma_f32_16x16x32_bf16(pa0, vl1, O1, 0, 0, 0);
            O1 = __builtin_amdgcn_mfma_f32_16x16x32_bf16(pa1, vh1, O1, 0, 0, 0);
            bf16x8 vl2 = *(const bf16x8*)&KV[buf][2][(2 * 16 + col) * 32 + quad * 8];
            bf16x8 vh2 = *(const bf16x8*)&KV[buf][3][(2 * 16 + col) * 32 + quad * 8];
            O2 = __builtin_amdgcn_mfma_f32_16x16x32_bf16(pa0, vl2, O2, 0, 0, 0);
            O2 = __builtin_amdgcn_mfma_f32_16x16x32_bf16(pa1, vh2, O2, 0, 0, 0);
            bf16x8 vl3 = *(const bf16x8*)&KV[buf][2][(3 * 16 + col) * 32 + quad * 8];
            bf16x8 vh3 = *(const bf16x8*)&KV[buf][3][(3 * 16 + col) * 32 + quad * 8];
            O3 = __builtin_amdgcn_mfma_f32_16x16x32_bf16(pa0, vl3, O3, 0, 0, 0);
            O3 = __builtin_amdgcn_mfma_f32_16x16x32_bf16(pa1, vh3, O3, 0, 0, 0);
        }
    }
#undef STAGE

    // reduce l across the 16 key-columns
#pragma unroll
    for (int off = 1; off < 16; off <<= 1)
#pragma unroll
        for (int r = 0; r < 4; ++r)
            lsum[r] += __shfl_xor(lsum[r], off);

    // merge partials: slot = hb*32 + X, row = wave*16 + quad*4 + r
    const int slot = hb * 32 + X;
    float* Ob = Oacc + ((size_t)slot * 64 + wave * 16) * 64;
    float* lb = lacc + (size_t)slot * 64 + wave * 16;
    if (sole) {
#pragma unroll
        for (int r = 0; r < 4; ++r) {
            float* rp = Ob + (quad * 4 + r) * 64;
            rp[col]      = O0[r];
            rp[16 + col] = O1[r];
            rp[32 + col] = O2[r];
            rp[48 + col] = O3[r];
            if (col == 0) lb[quad * 4 + r] = lsum[r];
        }
    } else {
#pragma unroll
        for (int r = 0; r < 4; ++r) {
            float* rp = Ob + (quad * 4 + r) * 64;
            atomicAdd(rp + col,      O0[r]);
            atomicAdd(rp + 16 + col, O1[r]);
            atomicAdd(rp + 32 + col, O2[r]);
            atomicAdd(rp + 48 + col, O3[r]);
            if (col == 0) atomicAdd(lb + quad * 4 + r, lsum[r]);
        }
    }
}

// ---------------------------------------------------------------------------
// Normalize partials: attnb[q][h*64+d] = Oacc[slot][q][d] / lacc[slot][q]
// ---------------------------------------------------------------------------
__global__ __launch_bounds__(256) void attn_norm(const float* __restrict__ Oacc,
                                                 const float* __restrict__ lacc,
                                                 short* __restrict__ attnb) {
    const int slot = blockIdx.x;             // 0..1023
    const int X  = slot & 31;
    const int hb = slot >> 5;
    const int h  = hb >> 1;
    const int b  = hb & 1;
    const int q  = threadIdx.x >> 2;         // 0..63
    const int d0 = (threadIdx.x & 3) * 16;

    const float inv = 1.f / lacc[(size_t)slot * 64 + q];
    const float* src = Oacc + ((size_t)slot * 64 + q) * 64 + d0;
    short* dst = attnb + (size_t)(b * SEQ + X * 64 + q) * NEMBD + h * HDIM + d0;

#pragma unroll
    for (int half = 0; half < 2; ++half) {
        float4 a = *(const float4*)(src + half * 8);
        float4 c = *(const float4*)(src + half * 8 + 4);
        bf16x8 o;
        o[0] = f2bf(a.x * inv); o[1] = f2bf(a.y * inv);
        o[2] = f2bf(a.z * inv); o[3] = f2bf(a.w * inv);
        o[4] = f2bf(c.x * inv); o[5] = f2bf(c.y * inv);
        o[6] = f2bf(c.z * inv); o[7] = f2bf(c.w * inv);
        *(bf16x8*)(dst + half * 8) = o;
    }
}

// ---------------------------------------------------------------------------
extern "C" void kernel_launch(void* const* d_in, const int* in_sizes, int n_in,
                              void* d_out, int out_size, void* d_ws, size_t ws_size,
                              hipStream_t stream) {
    const float* x      = (const float*)d_in[0];
    const float* w_qkv  = (const float*)d_in[1];
    const float* w_proj = (const float*)d_in[2];
    float* out = (float*)d_out;

    // ws layout: [xb | wqt | pad][qkvb][attnb][wpt]; Oacc (fp32, 16.78 MB)
    // overlays xb+wqt (dead after qkv GEMM). lacc in free half of d_out.
    char*  base  = (char*)d_ws;
    short* xb    = (short*)base;                            // 8.39 MB
    short* wqt   = xb + (size_t)MROWS * NEMBD;              // 6.29 MB
    float* Oacc  = (float*)base;                            // 16.78 MB overlay
    short* qkvb  = (short*)(base + (size_t)1024 * 4096 * 4);// @16.78, 25.17 MB
    short* attnb = qkvb + (size_t)MROWS * C3;               // @41.94, 8.39 MB
    short* wpt   = attnb + (size_t)MROWS * NEMBD;           // @50.33, 2.10 MB
    short* vt    = (short*)d_out;                           // 8.39 MB (free till proj)
    float* lacc  = (float*)((short*)d_out + (size_t)MROWS * NEMBD);  // 262 KB

    conv_x<<<dim3(MROWS * NEMBD / (256 * 8)), 256, 0, stream>>>(x, xb, MROWS * NEMBD);
    conv_wt<<<dim3(C3 / 64, NEMBD / 64), 256, 0, stream>>>(w_qkv, wqt, NEMBD, C3);
    conv_wt<<<dim3(NEMBD / 64, NEMBD / 64), 256, 0, stream>>>(w_proj, wpt, NEMBD, NEMBD);
    gemm_bt<short><<<dim3(C3 / 128, MROWS / 128), 256, 0, stream>>>(
        xb, wqt, qkvb, MROWS, C3, NEMBD);
    conv_vt<<<dim3(SEQ / 64, NHEAD, BATCH), 256, 0, stream>>>(qkvb, vt);
    // zero accumulators (xb/wqt dead from here on)
    hipMemsetAsync(Oacc, 0, (size_t)1024 * 4096 * 4, stream);
    hipMemsetAsync(lacc, 0, (size_t)1024 * 64 * 4, stream);
    attn_mfma<<<dim3(8, 32, 32), 256, 0, stream>>>(qkvb, vt, Oacc, lacc);
    attn_norm<<<dim3(1024), 256, 0, stream>>>(Oacc, lacc, attnb);
    gemm_bt<float><<<dim3(NEMBD / 128, MROWS / 128), 256, 0, stream>>>(
        attnb, wpt, out, MROWS, NEMBD, NEMBD);
}

// Round 9
// 200.223 us; speedup vs baseline: 1.1786x; 1.1786x over previous
//
#include <hip/hip_runtime.h>
#include <hip/hip_bf16.h>
#include <math.h>

// Problem constants
#define BATCH   2
#define SEQ     2048
#define NHEAD   16
#define HDIM    64
#define NEMBD   1024
#define C3      (3*NEMBD)
#define MROWS   (BATCH*SEQ)   // 4096

typedef short bf16x8 __attribute__((ext_vector_type(8)));
typedef float f32x4  __attribute__((ext_vector_type(4)));

static __device__ __forceinline__ short f2bf(float x) {
    union { __hip_bfloat16 h; short s; } u;
    u.h = __float2bfloat16(x);
    return u.s;
}

static __device__ __forceinline__ void stc(float* p, float v) { *p = v; }
static __device__ __forceinline__ void stc(short* p, float v) { *p = f2bf(v); }

// async global->LDS, 16B per lane. LDS dest = wave-uniform base + lane*16.
static __device__ __forceinline__ void gl_lds16(const short* g, short* lds_base) {
    __builtin_amdgcn_global_load_lds(
        (const __attribute__((address_space(1))) unsigned int*)g,
        (__attribute__((address_space(3))) unsigned int*)lds_base,
        16, 0, 0);
}

// ---------------------------------------------------------------------------
// Fused input converts (one launch):
//   blocks [0,2048):    x fp32 -> xb bf16 (8 elems/thread)
//   blocks [2048,2816): w_qkv [1024,3072] -> wqt [3072,1024] bf16 (transpose)
//   blocks [2816,3072): w_proj [1024,1024] -> wpt [1024,1024] bf16 (transpose)
// ---------------------------------------------------------------------------
__global__ __launch_bounds__(256) void conv_all(const float* __restrict__ x,
                                                const float* __restrict__ w_qkv,
                                                const float* __restrict__ w_proj,
                                                short* __restrict__ xb,
                                                short* __restrict__ wqt,
                                                short* __restrict__ wpt) {
    const int bid = blockIdx.x;
    if (bid < 2048) {
        const int i = (bid * 256 + (int)threadIdx.x) * 8;
        float4 a = *(const float4*)(x + i);
        float4 b = *(const float4*)(x + i + 4);
        bf16x8 o;
        o[0] = f2bf(a.x); o[1] = f2bf(a.y); o[2] = f2bf(a.z); o[3] = f2bf(a.w);
        o[4] = f2bf(b.x); o[5] = f2bf(b.y); o[6] = f2bf(b.z); o[7] = f2bf(b.w);
        *(bf16x8*)(xb + i) = o;
        return;
    }
    // weight transpose branch (whole block uniform)
    const float* in;
    short* out;
    int K, N, bx, by;
    if (bid < 2816) {
        const int id = bid - 2048;
        in = w_qkv; out = wqt; K = NEMBD; N = C3;
        bx = id % 48; by = id / 48;
    } else {
        const int id = bid - 2816;
        in = w_proj; out = wpt; K = NEMBD; N = NEMBD;
        bx = id % 16; by = id / 16;
    }
    __shared__ short tile[64][66];
    const int kt = by * 64, nt = bx * 64;
    const int r  = threadIdx.x / 4;
    const int c0 = (threadIdx.x % 4) * 16;

    const float* src = in + (size_t)(kt + r) * N + nt + c0;
#pragma unroll
    for (int c = 0; c < 16; c += 4) {
        float4 v = *(const float4*)(src + c);
        tile[r][c0 + c + 0] = f2bf(v.x);
        tile[r][c0 + c + 1] = f2bf(v.y);
        tile[r][c0 + c + 2] = f2bf(v.z);
        tile[r][c0 + c + 3] = f2bf(v.w);
    }
    __syncthreads();

    const int nr  = threadIdx.x / 4;
    const int k0c = (threadIdx.x % 4) * 16;
    bf16x8 o0, o1;
#pragma unroll
    for (int k = 0; k < 8; ++k) o0[k] = tile[k0c + k][nr];
#pragma unroll
    for (int k = 0; k < 8; ++k) o1[k] = tile[k0c + 8 + k][nr];
    short* dst = out + (size_t)(nt + nr) * K + kt + k0c;
    *(bf16x8*)dst       = o0;
    *(bf16x8*)(dst + 8) = o1;
}

// ---------------------------------------------------------------------------
// bf16 MFMA GEMM (m97 structure): C = A @ B, A [M,K], BT [N,K] bf16.
// ---------------------------------------------------------------------------
template <typename OT>
__global__ __launch_bounds__(256) void gemm_bt(const short* __restrict__ A,
                                               const short* __restrict__ BT,
                                               OT* __restrict__ C,
                                               int M, int N, int K) {
    __shared__ short As[128 * 32];
    __shared__ short Bs[128 * 32];

    const int tid  = threadIdx.x;
    const int wave = tid >> 6;
    const int lane = tid & 63;
    const int quad = lane >> 4;
    const int col  = lane & 15;
    const int m0 = blockIdx.y * 128;
    const int n0 = blockIdx.x * 128;
    const int mq = (wave >> 1) * 64;
    const int nq = (wave & 1) * 64;

    f32x4 acc[4][4] = {};

    const int cA  = wave * 64 + lane;
    const int cA1 = cA + 256;

    for (int k0 = 0; k0 < K; k0 += 32) {
        if (k0) __syncthreads();
        gl_lds16(A + (size_t)(m0 + (cA  >> 2)) * K + k0 + (cA  & 3) * 8,
                 &As[wave * 512]);
        gl_lds16(A + (size_t)(m0 + (cA1 >> 2)) * K + k0 + (cA1 & 3) * 8,
                 &As[2048 + wave * 512]);
        gl_lds16(BT + (size_t)(n0 + (cA  >> 2)) * K + k0 + (cA  & 3) * 8,
                 &Bs[wave * 512]);
        gl_lds16(BT + (size_t)(n0 + (cA1 >> 2)) * K + k0 + (cA1 & 3) * 8,
                 &Bs[2048 + wave * 512]);
        __syncthreads();

        bf16x8 af[4], bfr[4];
#pragma unroll
        for (int mt = 0; mt < 4; ++mt)
            af[mt] = *(const bf16x8*)&As[(mq + mt * 16 + col) * 32 + quad * 8];
#pragma unroll
        for (int nt = 0; nt < 4; ++nt)
            bfr[nt] = *(const bf16x8*)&Bs[(nq + nt * 16 + col) * 32 + quad * 8];
#pragma unroll
        for (int mt = 0; mt < 4; ++mt)
#pragma unroll
            for (int nt = 0; nt < 4; ++nt)
                acc[mt][nt] = __builtin_amdgcn_mfma_f32_16x16x32_bf16(
                    af[mt], bfr[nt], acc[mt][nt], 0, 0, 0);
    }

#pragma unroll
    for (int mt = 0; mt < 4; ++mt)
#pragma unroll
        for (int r = 0; r < 4; ++r) {
            const int row = m0 + mq + mt * 16 + quad * 4 + r;
            OT* cp = C + (size_t)row * N + n0 + nq + col;
#pragma unroll
            for (int nt = 0; nt < 4; ++nt)
                stc(cp + nt * 16, acc[mt][nt][r]);
        }
}

// ---------------------------------------------------------------------------
// V transpose: qkvb bf16 [B*T,3072] (v at 2048+h*64) -> vt [B*H][64][2048]
// ---------------------------------------------------------------------------
__global__ __launch_bounds__(256) void conv_vt(const short* __restrict__ qkvb,
                                               short* __restrict__ vt) {
    __shared__ short tile[64][66];
    const int b = blockIdx.z, h = blockIdx.y, t0 = blockIdx.x * 64;
    const int tt = threadIdx.x / 4;
    const int c0 = (threadIdx.x % 4) * 16;

    const short* src = qkvb + (size_t)(b * SEQ + t0 + tt) * C3 + 2 * NEMBD + h * HDIM + c0;
    bf16x8 v0 = *(const bf16x8*)src;
    bf16x8 v1 = *(const bf16x8*)(src + 8);
#pragma unroll
    for (int k = 0; k < 8; ++k) tile[tt][c0 + k]     = v0[k];
#pragma unroll
    for (int k = 0; k < 8; ++k) tile[tt][c0 + 8 + k] = v1[k];
    __syncthreads();

    const int d  = threadIdx.x / 4;
    const int tp = (threadIdx.x % 4) * 16;
    bf16x8 o0, o1;
#pragma unroll
    for (int k = 0; k < 8; ++k) o0[k] = tile[tp + k][d];
#pragma unroll
    for (int k = 0; k < 8; ++k) o1[k] = tile[tp + 8 + k][d];
    short* dst = vt + ((size_t)(b * NHEAD + h) * HDIM + d) * SEQ + t0 + tp;
    *(bf16x8*)dst       = o0;
    *(bf16x8*)(dst + 8) = o1;
}

// ---------------------------------------------------------------------------
// MFMA flash attention v6: key split into <=2 segments of 16 tiles, NO atomics.
// Fixed-max softmax p = exp2(qk*scale2 - slope2*j): partial (O,l) sums over
// disjoint key segments simply add. Single-seg slots (T<=16, the majority)
// normalize + write bf16 attnb in-kernel. Multi-seg slots (X>=16, untruncated)
// write fp32 partials to UNIQUE slots (no contention; R8's 10.5M atomicAdds
// were ~35us of serialized L2 traffic) merged by attn_merge.
// P uses a rotation swizzle (phys col = (k + rowquad*16) & 63): write bank
// conflicts 4-way -> 2-way (free, m136) with no padding -> stays 4 blocks/CU.
// ---------------------------------------------------------------------------
__global__ __launch_bounds__(256) void attn_mfma(const short* __restrict__ qkvb,
                                                 const short* __restrict__ vt,
                                                 short* __restrict__ attnb,
                                                 float* __restrict__ partO0,
                                                 float* __restrict__ partO1,
                                                 float* __restrict__ partl) {
    // [buf][region][64 rows * 32 shorts]; regions: 0=Klo 1=Khi 2=Vlo 3=Vhi
    __shared__ short KV[2][4][2048];     // 32 KB
    __shared__ short P_lds[4][16 * 64];  // 8 KB -> total 40 KB = 4 blocks/CU

    const int tid  = threadIdx.x;
    const int wave = tid >> 6;
    const int lane = tid & 63;
    const int quad = lane >> 4;
    const int col  = lane & 15;

    const int seg = blockIdx.x;              // 0 or 1 (16 tiles each)
    const int X   = 31 - (int)blockIdx.y;    // heavy-first
    const int hb  = blockIdx.z;              // = h*2 + b
    const int h   = hb >> 1;
    const int b   = hb & 1;

    const float LOG2E  = 1.4426950408889634f;
    const float scale2 = 0.125f * LOG2E;
    const float slope2 = exp2f(-0.5f * (float)(h + 1)) * LOG2E;

    const int Tneed = X + 1;
    const int Tcut  = ((int)(56.0f / slope2) >> 6) + 1;  // ALiBi truncation
    const int T     = Tneed < Tcut ? Tneed : Tcut;
    const int t0    = seg * 16;
    if (t0 >= T) return;                     // uniform early exit, before barriers
    const int tend  = min(t0 + 16, T);
    const bool sole = (T <= 16);             // single segment covers the slot

    const int q0 = X * 64 + wave * 16;

    const short* kb  = qkvb + (size_t)(b * SEQ) * C3 + NEMBD + h * HDIM;
    const short* vtb = vt + (size_t)(b * NHEAD + h) * HDIM * SEQ;

    // Q A-fragments: rows q0+col, dims quad*8 (+0 / +32)
    const short* qbase = qkvb + (size_t)(b * SEQ + q0 + col) * C3 + h * HDIM;
    const bf16x8 qa0 = *(const bf16x8*)(qbase + quad * 8);
    const bf16x8 qa1 = *(const bf16x8*)(qbase + 32 + quad * 8);

    f32x4 O0 = {0,0,0,0}, O1 = {0,0,0,0}, O2 = {0,0,0,0}, O3 = {0,0,0,0};
    float lsum[4] = {0.f, 0.f, 0.f, 0.f};
    short* P = P_lds[wave];

#define STAGE(t_, buf_) do {                                                   \
        const int jj = (t_) * 64;                                              \
        const int row = tid >> 2, g8 = (tid & 3) * 8;                          \
        gl_lds16(kb  + (size_t)(jj + row) * C3 + g8,      &KV[buf_][0][wave * 512]); \
        gl_lds16(kb  + (size_t)(jj + row) * C3 + 32 + g8, &KV[buf_][1][wave * 512]); \
        gl_lds16(vtb + (size_t)row * SEQ + jj + g8,       &KV[buf_][2][wave * 512]); \
        gl_lds16(vtb + (size_t)row * SEQ + jj + 32 + g8,  &KV[buf_][3][wave * 512]); \
    } while (0)

    STAGE(t0, 0);

    for (int t = t0; t < tend; ++t) {
        const int buf = (t - t0) & 1;
        __syncthreads();            // drains vmcnt -> buf ready; prev reads done
        if (t + 1 < tend) STAGE(t + 1, buf ^ 1);

        const int j0 = t * 64;

        // S = Q @ K^T from LDS K
        f32x4 S[4];
#pragma unroll
        for (int g = 0; g < 4; ++g) {
            bf16x8 k0 = *(const bf16x8*)&KV[buf][0][(g * 16 + col) * 32 + quad * 8];
            bf16x8 k1 = *(const bf16x8*)&KV[buf][1][(g * 16 + col) * 32 + quad * 8];
            f32x4 s = {0, 0, 0, 0};
            s = __builtin_amdgcn_mfma_f32_16x16x32_bf16(qa0, k0, s, 0, 0, 0);
            s = __builtin_amdgcn_mfma_f32_16x16x32_bf16(qa1, k1, s, 0, 0, 0);
            S[g] = s;
        }

        // softmax weights p = exp2(S*scale2 - slope2*j)
        const float cbase = -slope2 * (float)(j0 + col);
        const float d16   = -slope2 * 16.0f;
        float p[4][4];
        if (t == X) {               // diagonal tile: causal mask
#pragma unroll
            for (int g = 0; g < 4; ++g) {
                const float cg = cbase + d16 * (float)g;
                const int   jg = j0 + g * 16 + col;
#pragma unroll
                for (int r = 0; r < 4; ++r) {
                    const int i = q0 + quad * 4 + r;
                    p[g][r] = (jg <= i) ? exp2f(S[g][r] * scale2 + cg) : 0.f;
                }
            }
        } else {
#pragma unroll
            for (int g = 0; g < 4; ++g) {
                const float cg = cbase + d16 * (float)g;
#pragma unroll
                for (int r = 0; r < 4; ++r)
                    p[g][r] = exp2f(S[g][r] * scale2 + cg);
            }
        }
#pragma unroll
        for (int r = 0; r < 4; ++r)
            lsum[r] += (p[0][r] + p[1][r]) + (p[2][r] + p[3][r]);

        // P (C-layout) -> LDS [q][k] with rotation swizzle:
        // phys col = (k + (row>>2)*16) & 63; row>>2 == quad for the writer.
#pragma unroll
        for (int g = 0; g < 4; ++g)
#pragma unroll
            for (int r = 0; r < 4; ++r)
                P[(quad * 4 + r) * 64 + ((g * 16 + col + quad * 16) & 63)] = f2bf(p[g][r]);
        __asm__ volatile("s_waitcnt lgkmcnt(0)" ::: "memory");
        // reader of logical row q=col: rotation = (col>>2)*16
        const int rot = (col >> 2) * 16;
        bf16x8 pa0 = *(bf16x8*)&P[col * 64 + ((quad * 8 + rot) & 63)];
        bf16x8 pa1 = *(bf16x8*)&P[col * 64 + ((quad * 8 + 32 + rot) & 63)];
        __asm__ volatile("" ::: "memory");

        // O += P @ V: V^T B-fragments from LDS
        {
            bf16x8 vl0 = *(const bf16x8*)&KV[buf][2][(0 * 16 + col) * 32 + quad * 8];
            bf16x8 vh0 = *(const bf16x8*)&KV[buf][3][(0 * 16 + col) * 32 + quad * 8];
            O0 = __builtin_amdgcn_mfma_f32_16x16x32_bf16(pa0, vl0, O0, 0, 0, 0);
            O0 = __builtin_amdgcn_mfma_f32_16x16x32_bf16(pa1, vh0, O0, 0, 0, 0);
            bf16x8 vl1 = *(const bf16x8*)&KV[buf][2][(1 * 16 + col) * 32 + quad * 8];
            bf16x8 vh1 = *(const bf16x8*)&KV[buf][3][(1 * 16 + col) * 32 + quad * 8];
            O1 = __builtin_amdgcn_mfma_f32_16x16x32_bf16(pa0, vl1, O1, 0, 0, 0);
            O1 = __builtin_amdgcn_mfma_f32_16x16x32_bf16(pa1, vh1, O1, 0, 0, 0);
            bf16x8 vl2 = *(const bf16x8*)&KV[buf][2][(2 * 16 + col) * 32 + quad * 8];
            bf16x8 vh2 = *(const bf16x8*)&KV[buf][3][(2 * 16 + col) * 32 + quad * 8];
            O2 = __builtin_amdgcn_mfma_f32_16x16x32_bf16(pa0, vl2, O2, 0, 0, 0);
            O2 = __builtin_amdgcn_mfma_f32_16x16x32_bf16(pa1, vh2, O2, 0, 0, 0);
            bf16x8 vl3 = *(const bf16x8*)&KV[buf][2][(3 * 16 + col) * 32 + quad * 8];
            bf16x8 vh3 = *(const bf16x8*)&KV[buf][3][(3 * 16 + col) * 32 + quad * 8];
            O3 = __builtin_amdgcn_mfma_f32_16x16x32_bf16(pa0, vl3, O3, 0, 0, 0);
            O3 = __builtin_amdgcn_mfma_f32_16x16x32_bf16(pa1, vh3, O3, 0, 0, 0);
        }
    }
#undef STAGE

    // reduce l across the 16 key-columns
#pragma unroll
    for (int off = 1; off < 16; off <<= 1)
#pragma unroll
        for (int r = 0; r < 4; ++r)
            lsum[r] += __shfl_xor(lsum[r], off);

    if (sole) {
        // normalize + write bf16 attnb directly (R5 epilogue)
#pragma unroll
        for (int r = 0; r < 4; ++r) {
            const float inv = 1.f / lsum[r];
            const int row = q0 + quad * 4 + r;
            short* op = attnb + (size_t)(b * SEQ + row) * NEMBD + h * HDIM;
            op[col]      = f2bf(O0[r] * inv);
            op[16 + col] = f2bf(O1[r] * inv);
            op[32 + col] = f2bf(O2[r] * inv);
            op[48 + col] = f2bf(O3[r] * inv);
        }
    } else {
        // unique partial slot: pslot = hb*16 + (X-16)   (T>16 implies X>=16)
        const int pslot = hb * 16 + (X - 16);
        float* pO = ((seg == 0) ? partO0 : partO1) + (size_t)pslot * 4096
                    + (size_t)(wave * 16) * 64;
        float* pl = partl + (size_t)pslot * 128 + seg * 64 + wave * 16;
#pragma unroll
        for (int r = 0; r < 4; ++r) {
            float* rp = pO + (quad * 4 + r) * 64;
            rp[col]      = O0[r];
            rp[16 + col] = O1[r];
            rp[32 + col] = O2[r];
            rp[48 + col] = O3[r];
            if (col == 0) pl[quad * 4 + r] = lsum[r];
        }
    }
}

// ---------------------------------------------------------------------------
// Merge the two partial segments of split slots, normalize, write bf16 attnb.
// Grid 512 = pslots (hb*16 + X-16); slots that weren't split exit.
// ---------------------------------------------------------------------------
__global__ __launch_bounds__(256) void attn_merge(const float* __restrict__ partO0,
                                                  const float* __restrict__ partO1,
                                                  const float* __restrict__ partl,
                                                  short* __restrict__ attnb) {
    const int pslot = blockIdx.x;
    const int hb = pslot >> 4;
    const int X  = 16 + (pslot & 15);
    const int h  = hb >> 1;
    const int b  = hb & 1;

    const float LOG2E  = 1.4426950408889634f;
    const float slope2 = exp2f(-0.5f * (float)(h + 1)) * LOG2E;
    const int Tcut = ((int)(56.0f / slope2) >> 6) + 1;
    const int T = min(X + 1, Tcut);
    if (T <= 16) return;                      // slot was not split

    const int q  = threadIdx.x >> 2;          // 0..63
    const int d0 = (threadIdx.x & 3) * 16;

    const float l = partl[(size_t)pslot * 128 + q] + partl[(size_t)pslot * 128 + 64 + q];
    const float inv = 1.f / l;
    const float* s0 = partO0 + (size_t)pslot * 4096 + q * 64 + d0;
    const float* s1 = partO1 + (size_t)pslot * 4096 + q * 64 + d0;
    short* dst = attnb + (size_t)(b * SEQ + X * 64 + q) * NEMBD + h * HDIM + d0;

#pragma unroll
    for (int half = 0; half < 2; ++half) {
        float4 a0 = *(const float4*)(s0 + half * 8);
        float4 a1 = *(const float4*)(s0 + half * 8 + 4);
        float4 c0 = *(const float4*)(s1 + half * 8);
        float4 c1 = *(const float4*)(s1 + half * 8 + 4);
        bf16x8 o;
        o[0] = f2bf((a0.x + c0.x) * inv); o[1] = f2bf((a0.y + c0.y) * inv);
        o[2] = f2bf((a0.z + c0.z) * inv); o[3] = f2bf((a0.w + c0.w) * inv);
        o[4] = f2bf((a1.x + c1.x) * inv); o[5] = f2bf((a1.y + c1.y) * inv);
        o[6] = f2bf((a1.z + c1.z) * inv); o[7] = f2bf((a1.w + c1.w) * inv);
        *(bf16x8*)(dst + half * 8) = o;
    }
}

// ---------------------------------------------------------------------------
extern "C" void kernel_launch(void* const* d_in, const int* in_sizes, int n_in,
                              void* d_out, int out_size, void* d_ws, size_t ws_size,
                              hipStream_t stream) {
    const float* x      = (const float*)d_in[0];
    const float* w_qkv  = (const float*)d_in[1];
    const float* w_proj = (const float*)d_in[2];
    float* out = (float*)d_out;

    // ws layout: [xb 8.39 | wqt 6.29 | pad][qkvb 25.17][attnb 8.39][wpt 2.10]
    // After qkv GEMM, xb/wqt are dead: partO0 overlays xb (512*16KB = 8.39MB),
    // partl overlays wqt (256KB). partO1 lives in the free half of d_out.
    char*  base  = (char*)d_ws;
    short* xb    = (short*)base;
    short* wqt   = xb + (size_t)MROWS * NEMBD;
    float* partO0 = (float*)base;                            // 8.39 MB overlay
    float* partl  = (float*)(base + (size_t)MROWS * NEMBD * 2);  // over wqt
    short* qkvb  = (short*)(base + (size_t)1024 * 4096 * 4); // @16.78 MB
    short* attnb = qkvb + (size_t)MROWS * C3;                // @41.94 MB
    short* wpt   = attnb + (size_t)MROWS * NEMBD;            // @50.33 MB
    short* vt    = (short*)d_out;                            // 8.39 MB
    float* partO1 = (float*)((short*)d_out + (size_t)MROWS * NEMBD);  // 8.39 MB

    conv_all<<<dim3(3072), 256, 0, stream>>>(x, w_qkv, w_proj, xb, wqt, wpt);
    gemm_bt<short><<<dim3(C3 / 128, MROWS / 128), 256, 0, stream>>>(
        xb, wqt, qkvb, MROWS, C3, NEMBD);
    conv_vt<<<dim3(SEQ / 64, NHEAD, BATCH), 256, 0, stream>>>(qkvb, vt);
    attn_mfma<<<dim3(2, 32, 32), 256, 0, stream>>>(qkvb, vt, attnb,
                                                   partO0, partO1, partl);
    attn_merge<<<dim3(512), 256, 0, stream>>>(partO0, partO1, partl, attnb);
    gemm_bt<float><<<dim3(NEMBD / 128, MROWS / 128), 256, 0, stream>>>(
        attnb, wpt, out, MROWS, NEMBD, NEMBD);
}

// Round 10
// 192.715 us; speedup vs baseline: 1.2246x; 1.0390x over previous
//
#include <hip/hip_runtime.h>
#include <hip/hip_bf16.h>
#include <math.h>

// Problem constants
#define BATCH   2
#define SEQ     2048
#define NHEAD   16
#define HDIM    64
#define NEMBD   1024
#define C3      (3*NEMBD)
#define MROWS   (BATCH*SEQ)   // 4096

typedef short bf16x8 __attribute__((ext_vector_type(8)));
typedef float f32x4  __attribute__((ext_vector_type(4)));

static __device__ __forceinline__ short f2bf(float x) {
    union { __hip_bfloat16 h; short s; } u;
    u.h = __float2bfloat16(x);
    return u.s;
}

static __device__ __forceinline__ void stc(float* p, float v) { *p = v; }
static __device__ __forceinline__ void stc(short* p, float v) { *p = f2bf(v); }

// async global->LDS, 16B per lane. LDS dest = wave-uniform base + lane*16.
static __device__ __forceinline__ void gl_lds16(const short* g, short* lds_base) {
    __builtin_amdgcn_global_load_lds(
        (const __attribute__((address_space(1))) unsigned int*)g,
        (__attribute__((address_space(3))) unsigned int*)lds_base,
        16, 0, 0);
}

// ALiBi truncation margin (exp2 units): dropped keys contribute
// <= 2^(4.8-MARGIN) rel. each vs lsum>=2^-2.4; x2048 keys ~2^-14 rel. total.
#define ALIBI_MARGIN 30.0f

// ---------------------------------------------------------------------------
// Fused input converts (one launch):
//   blocks [0,2048):    x fp32 -> xb bf16 (8 elems/thread)
//   blocks [2048,2816): w_qkv [1024,3072] -> wqt [3072,1024] bf16 (transpose)
//   blocks [2816,3072): w_proj [1024,1024] -> wpt [1024,1024] bf16 (transpose)
// ---------------------------------------------------------------------------
__global__ __launch_bounds__(256) void conv_all(const float* __restrict__ x,
                                                const float* __restrict__ w_qkv,
                                                const float* __restrict__ w_proj,
                                                short* __restrict__ xb,
                                                short* __restrict__ wqt,
                                                short* __restrict__ wpt) {
    const int bid = blockIdx.x;
    if (bid < 2048) {
        const int i = (bid * 256 + (int)threadIdx.x) * 8;
        float4 a = *(const float4*)(x + i);
        float4 b = *(const float4*)(x + i + 4);
        bf16x8 o;
        o[0] = f2bf(a.x); o[1] = f2bf(a.y); o[2] = f2bf(a.z); o[3] = f2bf(a.w);
        o[4] = f2bf(b.x); o[5] = f2bf(b.y); o[6] = f2bf(b.z); o[7] = f2bf(b.w);
        *(bf16x8*)(xb + i) = o;
        return;
    }
    // weight transpose branch (whole block uniform)
    const float* in;
    short* out;
    int K, N, bx, by;
    if (bid < 2816) {
        const int id = bid - 2048;
        in = w_qkv; out = wqt; K = NEMBD; N = C3;
        bx = id % 48; by = id / 48;
    } else {
        const int id = bid - 2816;
        in = w_proj; out = wpt; K = NEMBD; N = NEMBD;
        bx = id % 16; by = id / 16;
    }
    __shared__ short tile[64][66];
    const int kt = by * 64, nt = bx * 64;
    const int r  = threadIdx.x / 4;
    const int c0 = (threadIdx.x % 4) * 16;

    const float* src = in + (size_t)(kt + r) * N + nt + c0;
#pragma unroll
    for (int c = 0; c < 16; c += 4) {
        float4 v = *(const float4*)(src + c);
        tile[r][c0 + c + 0] = f2bf(v.x);
        tile[r][c0 + c + 1] = f2bf(v.y);
        tile[r][c0 + c + 2] = f2bf(v.z);
        tile[r][c0 + c + 3] = f2bf(v.w);
    }
    __syncthreads();

    const int nr  = threadIdx.x / 4;
    const int k0c = (threadIdx.x % 4) * 16;
    bf16x8 o0, o1;
#pragma unroll
    for (int k = 0; k < 8; ++k) o0[k] = tile[k0c + k][nr];
#pragma unroll
    for (int k = 0; k < 8; ++k) o1[k] = tile[k0c + 8 + k][nr];
    short* dst = out + (size_t)(nt + nr) * K + kt + k0c;
    *(bf16x8*)dst       = o0;
    *(bf16x8*)(dst + 8) = o1;
}

// ---------------------------------------------------------------------------
// bf16 MFMA GEMM (m97 structure): C = A @ B, A [M,K], BT [N,K] bf16.
// ---------------------------------------------------------------------------
template <typename OT>
__global__ __launch_bounds__(256) void gemm_bt(const short* __restrict__ A,
                                               const short* __restrict__ BT,
                                               OT* __restrict__ C,
                                               int M, int N, int K) {
    __shared__ short As[128 * 32];
    __shared__ short Bs[128 * 32];

    const int tid  = threadIdx.x;
    const int wave = tid >> 6;
    const int lane = tid & 63;
    const int quad = lane >> 4;
    const int col  = lane & 15;
    const int m0 = blockIdx.y * 128;
    const int n0 = blockIdx.x * 128;
    const int mq = (wave >> 1) * 64;
    const int nq = (wave & 1) * 64;

    f32x4 acc[4][4] = {};

    const int cA  = wave * 64 + lane;
    const int cA1 = cA + 256;

    for (int k0 = 0; k0 < K; k0 += 32) {
        if (k0) __syncthreads();
        gl_lds16(A + (size_t)(m0 + (cA  >> 2)) * K + k0 + (cA  & 3) * 8,
                 &As[wave * 512]);
        gl_lds16(A + (size_t)(m0 + (cA1 >> 2)) * K + k0 + (cA1 & 3) * 8,
                 &As[2048 + wave * 512]);
        gl_lds16(BT + (size_t)(n0 + (cA  >> 2)) * K + k0 + (cA  & 3) * 8,
                 &Bs[wave * 512]);
        gl_lds16(BT + (size_t)(n0 + (cA1 >> 2)) * K + k0 + (cA1 & 3) * 8,
                 &Bs[2048 + wave * 512]);
        __syncthreads();

        bf16x8 af[4], bfr[4];
#pragma unroll
        for (int mt = 0; mt < 4; ++mt)
            af[mt] = *(const bf16x8*)&As[(mq + mt * 16 + col) * 32 + quad * 8];
#pragma unroll
        for (int nt = 0; nt < 4; ++nt)
            bfr[nt] = *(const bf16x8*)&Bs[(nq + nt * 16 + col) * 32 + quad * 8];
#pragma unroll
        for (int mt = 0; mt < 4; ++mt)
#pragma unroll
            for (int nt = 0; nt < 4; ++nt)
                acc[mt][nt] = __builtin_amdgcn_mfma_f32_16x16x32_bf16(
                    af[mt], bfr[nt], acc[mt][nt], 0, 0, 0);
    }

#pragma unroll
    for (int mt = 0; mt < 4; ++mt)
#pragma unroll
        for (int r = 0; r < 4; ++r) {
            const int row = m0 + mq + mt * 16 + quad * 4 + r;
            OT* cp = C + (size_t)row * N + n0 + nq + col;
#pragma unroll
            for (int nt = 0; nt < 4; ++nt)
                stc(cp + nt * 16, acc[mt][nt][r]);
        }
}

// ---------------------------------------------------------------------------
// V transpose: qkvb bf16 [B*T,3072] (v at 2048+h*64) -> vt [B*H][64][2048]
// ---------------------------------------------------------------------------
__global__ __launch_bounds__(256) void conv_vt(const short* __restrict__ qkvb,
                                               short* __restrict__ vt) {
    __shared__ short tile[64][66];
    const int b = blockIdx.z, h = blockIdx.y, t0 = blockIdx.x * 64;
    const int tt = threadIdx.x / 4;
    const int c0 = (threadIdx.x % 4) * 16;

    const short* src = qkvb + (size_t)(b * SEQ + t0 + tt) * C3 + 2 * NEMBD + h * HDIM + c0;
    bf16x8 v0 = *(const bf16x8*)src;
    bf16x8 v1 = *(const bf16x8*)(src + 8);
#pragma unroll
    for (int k = 0; k < 8; ++k) tile[tt][c0 + k]     = v0[k];
#pragma unroll
    for (int k = 0; k < 8; ++k) tile[tt][c0 + 8 + k] = v1[k];
    __syncthreads();

    const int d  = threadIdx.x / 4;
    const int tp = (threadIdx.x % 4) * 16;
    bf16x8 o0, o1;
#pragma unroll
    for (int k = 0; k < 8; ++k) o0[k] = tile[tp + k][d];
#pragma unroll
    for (int k = 0; k < 8; ++k) o1[k] = tile[tp + 8 + k][d];
    short* dst = vt + ((size_t)(b * NHEAD + h) * HDIM + d) * SEQ + t0 + tp;
    *(bf16x8*)dst       = o0;
    *(bf16x8*)(dst + 8) = o1;
}

// ---------------------------------------------------------------------------
// MFMA flash attention v7 (= v6 + global heavy-first + margin 30).
// Key split into <=2 segments of 16 tiles, NO atomics; fixed-max softmax
// p = exp2(qk*scale2 - slope2*j): partial (O,l) sums over disjoint segments
// simply add. Single-seg slots normalize + write bf16 attnb in-kernel;
// split slots write fp32 partials to unique slots, merged by attn_merge.
// Grid (hb, seg, Xi): hb FASTEST, X=31-Xi SLOWEST-desc -> all heavy 16-tile
// segments (every head/batch) dispatch first; 1-tile trivia fill the tail.
// (R9 had hb slowest: per-head heavy-first only -> h=15's heavies dispatched
// last -> 15% time-avg occupancy. This is the fix.)
// ---------------------------------------------------------------------------
__global__ __launch_bounds__(256) void attn_mfma(const short* __restrict__ qkvb,
                                                 const short* __restrict__ vt,
                                                 short* __restrict__ attnb,
                                                 float* __restrict__ partO0,
                                                 float* __restrict__ partO1,
                                                 float* __restrict__ partl) {
    // [buf][region][64 rows * 32 shorts]; regions: 0=Klo 1=Khi 2=Vlo 3=Vhi
    __shared__ short KV[2][4][2048];     // 32 KB
    __shared__ short P_lds[4][16 * 64];  // 8 KB -> total 40 KB = 4 blocks/CU

    const int tid  = threadIdx.x;
    const int wave = tid >> 6;
    const int lane = tid & 63;
    const int quad = lane >> 4;
    const int col  = lane & 15;

    const int hb  = blockIdx.x;              // FASTEST -> spreads heads
    const int seg = blockIdx.y;              // 0 or 1 (16 tiles each)
    const int X   = 31 - (int)blockIdx.z;    // SLOWEST, descending: global heavy-first
    const int h   = hb >> 1;
    const int b   = hb & 1;

    const float LOG2E  = 1.4426950408889634f;
    const float scale2 = 0.125f * LOG2E;
    const float slope2 = exp2f(-0.5f * (float)(h + 1)) * LOG2E;

    const int Tneed = X + 1;
    const int Tcut  = ((int)(ALIBI_MARGIN / slope2) >> 6) + 1;  // ALiBi truncation
    const int T     = Tneed < Tcut ? Tneed : Tcut;
    const int t0    = seg * 16;
    if (t0 >= T) return;                     // uniform early exit, before barriers
    const int tend  = min(t0 + 16, T);
    const bool sole = (T <= 16);             // single segment covers the slot

    const int q0 = X * 64 + wave * 16;

    const short* kb  = qkvb + (size_t)(b * SEQ) * C3 + NEMBD + h * HDIM;
    const short* vtb = vt + (size_t)(b * NHEAD + h) * HDIM * SEQ;

    // Q A-fragments: rows q0+col, dims quad*8 (+0 / +32)
    const short* qbase = qkvb + (size_t)(b * SEQ + q0 + col) * C3 + h * HDIM;
    const bf16x8 qa0 = *(const bf16x8*)(qbase + quad * 8);
    const bf16x8 qa1 = *(const bf16x8*)(qbase + 32 + quad * 8);

    f32x4 O0 = {0,0,0,0}, O1 = {0,0,0,0}, O2 = {0,0,0,0}, O3 = {0,0,0,0};
    float lsum[4] = {0.f, 0.f, 0.f, 0.f};
    short* P = P_lds[wave];

#define STAGE(t_, buf_) do {                                                   \
        const int jj = (t_) * 64;                                              \
        const int row = tid >> 2, g8 = (tid & 3) * 8;                          \
        gl_lds16(kb  + (size_t)(jj + row) * C3 + g8,      &KV[buf_][0][wave * 512]); \
        gl_lds16(kb  + (size_t)(jj + row) * C3 + 32 + g8, &KV[buf_][1][wave * 512]); \
        gl_lds16(vtb + (size_t)row * SEQ + jj + g8,       &KV[buf_][2][wave * 512]); \
        gl_lds16(vtb + (size_t)row * SEQ + jj + 32 + g8,  &KV[buf_][3][wave * 512]); \
    } while (0)

    STAGE(t0, 0);

    for (int t = t0; t < tend; ++t) {
        const int buf = (t - t0) & 1;
        __syncthreads();            // drains vmcnt -> buf ready; prev reads done
        if (t + 1 < tend) STAGE(t + 1, buf ^ 1);

        const int j0 = t * 64;

        // S = Q @ K^T from LDS K
        f32x4 S[4];
#pragma unroll
        for (int g = 0; g < 4; ++g) {
            bf16x8 k0 = *(const bf16x8*)&KV[buf][0][(g * 16 + col) * 32 + quad * 8];
            bf16x8 k1 = *(const bf16x8*)&KV[buf][1][(g * 16 + col) * 32 + quad * 8];
            f32x4 s = {0, 0, 0, 0};
            s = __builtin_amdgcn_mfma_f32_16x16x32_bf16(qa0, k0, s, 0, 0, 0);
            s = __builtin_amdgcn_mfma_f32_16x16x32_bf16(qa1, k1, s, 0, 0, 0);
            S[g] = s;
        }

        // softmax weights p = exp2(S*scale2 - slope2*j)
        const float cbase = -slope2 * (float)(j0 + col);
        const float d16   = -slope2 * 16.0f;
        float p[4][4];
        if (t == X) {               // diagonal tile: causal mask
#pragma unroll
            for (int g = 0; g < 4; ++g) {
                const float cg = cbase + d16 * (float)g;
                const int   jg = j0 + g * 16 + col;
#pragma unroll
                for (int r = 0; r < 4; ++r) {
                    const int i = q0 + quad * 4 + r;
                    p[g][r] = (jg <= i) ? exp2f(S[g][r] * scale2 + cg) : 0.f;
                }
            }
        } else {
#pragma unroll
            for (int g = 0; g < 4; ++g) {
                const float cg = cbase + d16 * (float)g;
#pragma unroll
                for (int r = 0; r < 4; ++r)
                    p[g][r] = exp2f(S[g][r] * scale2 + cg);
            }
        }
#pragma unroll
        for (int r = 0; r < 4; ++r)
            lsum[r] += (p[0][r] + p[1][r]) + (p[2][r] + p[3][r]);

        // P (C-layout) -> LDS [q][k] with rotation swizzle:
        // phys col = (k + (row>>2)*16) & 63; row>>2 == quad for the writer.
#pragma unroll
        for (int g = 0; g < 4; ++g)
#pragma unroll
            for (int r = 0; r < 4; ++r)
                P[(quad * 4 + r) * 64 + ((g * 16 + col + quad * 16) & 63)] = f2bf(p[g][r]);
        __asm__ volatile("s_waitcnt lgkmcnt(0)" ::: "memory");
        // reader of logical row q=col: rotation = (col>>2)*16
        const int rot = (col >> 2) * 16;
        bf16x8 pa0 = *(bf16x8*)&P[col * 64 + ((quad * 8 + rot) & 63)];
        bf16x8 pa1 = *(bf16x8*)&P[col * 64 + ((quad * 8 + 32 + rot) & 63)];
        __asm__ volatile("" ::: "memory");

        // O += P @ V: V^T B-fragments from LDS
        {
            bf16x8 vl0 = *(const bf16x8*)&KV[buf][2][(0 * 16 + col) * 32 + quad * 8];
            bf16x8 vh0 = *(const bf16x8*)&KV[buf][3][(0 * 16 + col) * 32 + quad * 8];
            O0 = __builtin_amdgcn_mfma_f32_16x16x32_bf16(pa0, vl0, O0, 0, 0, 0);
            O0 = __builtin_amdgcn_mfma_f32_16x16x32_bf16(pa1, vh0, O0, 0, 0, 0);
            bf16x8 vl1 = *(const bf16x8*)&KV[buf][2][(1 * 16 + col) * 32 + quad * 8];
            bf16x8 vh1 = *(const bf16x8*)&KV[buf][3][(1 * 16 + col) * 32 + quad * 8];
            O1 = __builtin_amdgcn_mfma_f32_16x16x32_bf16(pa0, vl1, O1, 0, 0, 0);
            O1 = __builtin_amdgcn_mfma_f32_16x16x32_bf16(pa1, vh1, O1, 0, 0, 0);
            bf16x8 vl2 = *(const bf16x8*)&KV[buf][2][(2 * 16 + col) * 32 + quad * 8];
            bf16x8 vh2 = *(const bf16x8*)&KV[buf][3][(2 * 16 + col) * 32 + quad * 8];
            O2 = __builtin_amdgcn_mfma_f32_16x16x32_bf16(pa0, vl2, O2, 0, 0, 0);
            O2 = __builtin_amdgcn_mfma_f32_16x16x32_bf16(pa1, vh2, O2, 0, 0, 0);
            bf16x8 vl3 = *(const bf16x8*)&KV[buf][2][(3 * 16 + col) * 32 + quad * 8];
            bf16x8 vh3 = *(const bf16x8*)&KV[buf][3][(3 * 16 + col) * 32 + quad * 8];
            O3 = __builtin_amdgcn_mfma_f32_16x16x32_bf16(pa0, vl3, O3, 0, 0, 0);
            O3 = __builtin_amdgcn_mfma_f32_16x16x32_bf16(pa1, vh3, O3, 0, 0, 0);
        }
    }
#undef STAGE

    // reduce l across the 16 key-columns
#pragma unroll
    for (int off = 1; off < 16; off <<= 1)
#pragma unroll
        for (int r = 0; r < 4; ++r)
            lsum[r] += __shfl_xor(lsum[r], off);

    if (sole) {
        // normalize + write bf16 attnb directly
#pragma unroll
        for (int r = 0; r < 4; ++r) {
            const float inv = 1.f / lsum[r];
            const int row = q0 + quad * 4 + r;
            short* op = attnb + (size_t)(b * SEQ + row) * NEMBD + h * HDIM;
            op[col]      = f2bf(O0[r] * inv);
            op[16 + col] = f2bf(O1[r] * inv);
            op[32 + col] = f2bf(O2[r] * inv);
            op[48 + col] = f2bf(O3[r] * inv);
        }
    } else {
        // unique partial slot: pslot = hb*16 + (X-16)   (T>16 implies X>=16)
        const int pslot = hb * 16 + (X - 16);
        float* pO = ((seg == 0) ? partO0 : partO1) + (size_t)pslot * 4096
                    + (size_t)(wave * 16) * 64;
        float* pl = partl + (size_t)pslot * 128 + seg * 64 + wave * 16;
#pragma unroll
        for (int r = 0; r < 4; ++r) {
            float* rp = pO + (quad * 4 + r) * 64;
            rp[col]      = O0[r];
            rp[16 + col] = O1[r];
            rp[32 + col] = O2[r];
            rp[48 + col] = O3[r];
            if (col == 0) pl[quad * 4 + r] = lsum[r];
        }
    }
}

// ---------------------------------------------------------------------------
// Merge the two partial segments of split slots, normalize, write bf16 attnb.
// Grid 512 = pslots (hb*16 + X-16); slots that weren't split exit.
// ---------------------------------------------------------------------------
__global__ __launch_bounds__(256) void attn_merge(const float* __restrict__ partO0,
                                                  const float* __restrict__ partO1,
                                                  const float* __restrict__ partl,
                                                  short* __restrict__ attnb) {
    const int pslot = blockIdx.x;
    const int hb = pslot >> 4;
    const int X  = 16 + (pslot & 15);
    const int h  = hb >> 1;
    const int b  = hb & 1;

    const float LOG2E  = 1.4426950408889634f;
    const float slope2 = exp2f(-0.5f * (float)(h + 1)) * LOG2E;
    const int Tcut = ((int)(ALIBI_MARGIN / slope2) >> 6) + 1;
    const int T = min(X + 1, Tcut);
    if (T <= 16) return;                      // slot was not split

    const int q  = threadIdx.x >> 2;          // 0..63
    const int d0 = (threadIdx.x & 3) * 16;

    const float l = partl[(size_t)pslot * 128 + q] + partl[(size_t)pslot * 128 + 64 + q];
    const float inv = 1.f / l;
    const float* s0 = partO0 + (size_t)pslot * 4096 + q * 64 + d0;
    const float* s1 = partO1 + (size_t)pslot * 4096 + q * 64 + d0;
    short* dst = attnb + (size_t)(b * SEQ + X * 64 + q) * NEMBD + h * HDIM + d0;

#pragma unroll
    for (int half = 0; half < 2; ++half) {
        float4 a0 = *(const float4*)(s0 + half * 8);
        float4 a1 = *(const float4*)(s0 + half * 8 + 4);
        float4 c0 = *(const float4*)(s1 + half * 8);
        float4 c1 = *(const float4*)(s1 + half * 8 + 4);
        bf16x8 o;
        o[0] = f2bf((a0.x + c0.x) * inv); o[1] = f2bf((a0.y + c0.y) * inv);
        o[2] = f2bf((a0.z + c0.z) * inv); o[3] = f2bf((a0.w + c0.w) * inv);
        o[4] = f2bf((a1.x + c1.x) * inv); o[5] = f2bf((a1.y + c1.y) * inv);
        o[6] = f2bf((a1.z + c1.z) * inv); o[7] = f2bf((a1.w + c1.w) * inv);
        *(bf16x8*)(dst + half * 8) = o;
    }
}

// ---------------------------------------------------------------------------
extern "C" void kernel_launch(void* const* d_in, const int* in_sizes, int n_in,
                              void* d_out, int out_size, void* d_ws, size_t ws_size,
                              hipStream_t stream) {
    const float* x      = (const float*)d_in[0];
    const float* w_qkv  = (const float*)d_in[1];
    const float* w_proj = (const float*)d_in[2];
    float* out = (float*)d_out;

    // ws layout: [xb 8.39 | wqt 6.29 | pad][qkvb 25.17][attnb 8.39][wpt 2.10]
    // After qkv GEMM, xb/wqt are dead: partO0 overlays xb (512*16KB = 8.39MB),
    // partl overlays wqt (256KB). partO1 lives in the free half of d_out.
    char*  base  = (char*)d_ws;
    short* xb    = (short*)base;
    short* wqt   = xb + (size_t)MROWS * NEMBD;
    float* partO0 = (float*)base;                            // 8.39 MB overlay
    float* partl  = (float*)(base + (size_t)MROWS * NEMBD * 2);  // over wqt
    short* qkvb  = (short*)(base + (size_t)1024 * 4096 * 4); // @16.78 MB
    short* attnb = qkvb + (size_t)MROWS * C3;                // @41.94 MB
    short* wpt   = attnb + (size_t)MROWS * NEMBD;            // @50.33 MB
    short* vt    = (short*)d_out;                            // 8.39 MB
    float* partO1 = (float*)((short*)d_out + (size_t)MROWS * NEMBD);  // 8.39 MB

    conv_all<<<dim3(3072), 256, 0, stream>>>(x, w_qkv, w_proj, xb, wqt, wpt);
    gemm_bt<short><<<dim3(C3 / 128, MROWS / 128), 256, 0, stream>>>(
        xb, wqt, qkvb, MROWS, C3, NEMBD);
    conv_vt<<<dim3(SEQ / 64, NHEAD, BATCH), 256, 0, stream>>>(qkvb, vt);
    attn_mfma<<<dim3(32, 2, 32), 256, 0, stream>>>(qkvb, vt, attnb,
                                                   partO0, partO1, partl);
    attn_merge<<<dim3(512), 256, 0, stream>>>(partO0, partO1, partl, attnb);
    gemm_bt<float><<<dim3(NEMBD / 128, MROWS / 128), 256, 0, stream>>>(
        attnb, wpt, out, MROWS, NEMBD, NEMBD);
}

// Round 11
// 190.107 us; speedup vs baseline: 1.2414x; 1.0137x over previous
//
#include <hip/hip_runtime.h>
#include <hip/hip_bf16.h>
#include <math.h>

// Problem constants
#define BATCH   2
#define SEQ     2048
#define NHEAD   16
#define HDIM    64
#define NEMBD   1024
#define C3      (3*NEMBD)
#define MROWS   (BATCH*SEQ)   // 4096

typedef short bf16x8 __attribute__((ext_vector_type(8)));
typedef short bf16x4 __attribute__((ext_vector_type(4)));
typedef float f32x4  __attribute__((ext_vector_type(4)));

static __device__ __forceinline__ short f2bf(float x) {
    union { __hip_bfloat16 h; short s; } u;
    u.h = __float2bfloat16(x);
    return u.s;
}

static __device__ __forceinline__ void stc(float* p, float v) { *p = v; }
static __device__ __forceinline__ void stc(short* p, float v) { *p = f2bf(v); }

// async global->LDS, 16B per lane. LDS dest = wave-uniform base + lane*16.
static __device__ __forceinline__ void gl_lds16(const short* g, short* lds_base) {
    __builtin_amdgcn_global_load_lds(
        (const __attribute__((address_space(1))) unsigned int*)g,
        (__attribute__((address_space(3))) unsigned int*)lds_base,
        16, 0, 0);
}

// ALiBi truncation margin (exp2 units): dropped keys contribute
// <= 2^(4.8-MARGIN) rel. each vs lsum>=2^-2.4; x2048 keys ~2^-14 rel. total.
#define ALIBI_MARGIN 30.0f

// ---------------------------------------------------------------------------
// Fused input converts (one launch):
//   blocks [0,2048):    x fp32 -> xb bf16 (8 elems/thread)
//   blocks [2048,2816): w_qkv [1024,3072] -> wqt [3072,1024] bf16 (transpose)
//   blocks [2816,3072): w_proj [1024,1024] -> wpt [1024,1024] bf16 (transpose)
// ---------------------------------------------------------------------------
__global__ __launch_bounds__(256) void conv_all(const float* __restrict__ x,
                                                const float* __restrict__ w_qkv,
                                                const float* __restrict__ w_proj,
                                                short* __restrict__ xb,
                                                short* __restrict__ wqt,
                                                short* __restrict__ wpt) {
    const int bid = blockIdx.x;
    if (bid < 2048) {
        const int i = (bid * 256 + (int)threadIdx.x) * 8;
        float4 a = *(const float4*)(x + i);
        float4 b = *(const float4*)(x + i + 4);
        bf16x8 o;
        o[0] = f2bf(a.x); o[1] = f2bf(a.y); o[2] = f2bf(a.z); o[3] = f2bf(a.w);
        o[4] = f2bf(b.x); o[5] = f2bf(b.y); o[6] = f2bf(b.z); o[7] = f2bf(b.w);
        *(bf16x8*)(xb + i) = o;
        return;
    }
    const float* in;
    short* out;
    int K, N, bx, by;
    if (bid < 2816) {
        const int id = bid - 2048;
        in = w_qkv; out = wqt; K = NEMBD; N = C3;
        bx = id % 48; by = id / 48;
    } else {
        const int id = bid - 2816;
        in = w_proj; out = wpt; K = NEMBD; N = NEMBD;
        bx = id % 16; by = id / 16;
    }
    __shared__ short tile[64][66];
    const int kt = by * 64, nt = bx * 64;
    const int r  = threadIdx.x / 4;
    const int c0 = (threadIdx.x % 4) * 16;

    const float* src = in + (size_t)(kt + r) * N + nt + c0;
#pragma unroll
    for (int c = 0; c < 16; c += 4) {
        float4 v = *(const float4*)(src + c);
        tile[r][c0 + c + 0] = f2bf(v.x);
        tile[r][c0 + c + 1] = f2bf(v.y);
        tile[r][c0 + c + 2] = f2bf(v.z);
        tile[r][c0 + c + 3] = f2bf(v.w);
    }
    __syncthreads();

    const int nr  = threadIdx.x / 4;
    const int k0c = (threadIdx.x % 4) * 16;
    bf16x8 o0, o1;
#pragma unroll
    for (int k = 0; k < 8; ++k) o0[k] = tile[k0c + k][nr];
#pragma unroll
    for (int k = 0; k < 8; ++k) o1[k] = tile[k0c + 8 + k][nr];
    short* dst = out + (size_t)(nt + nr) * K + kt + k0c;
    *(bf16x8*)dst       = o0;
    *(bf16x8*)(dst + 8) = o1;
}

// ---------------------------------------------------------------------------
// bf16 MFMA GEMM (m97 structure): C = A @ B, A [M,K], BT [N,K] bf16.
// FUSE_VT (qkv GEMM only): blocks covering columns >= 2048 (the V part)
// write bf16 V^T [b*16+h][d][t] directly instead of C — lane's 4 consecutive
// acc rows are 4 consecutive t -> one bf16x4 store per acc tile. Removes the
// separate conv_vt kernel; qkvb's V columns are never read.
// ---------------------------------------------------------------------------
template <typename OT, bool FUSE_VT>
__global__ __launch_bounds__(256) void gemm_bt(const short* __restrict__ A,
                                               const short* __restrict__ BT,
                                               OT* __restrict__ C,
                                               int M, int N, int K,
                                               short* __restrict__ vt) {
    __shared__ short As[128 * 32];
    __shared__ short Bs[128 * 32];

    const int tid  = threadIdx.x;
    const int wave = tid >> 6;
    const int lane = tid & 63;
    const int quad = lane >> 4;
    const int col  = lane & 15;
    const int m0 = blockIdx.y * 128;
    const int n0 = blockIdx.x * 128;
    const int mq = (wave >> 1) * 64;
    const int nq = (wave & 1) * 64;

    f32x4 acc[4][4] = {};

    const int cA  = wave * 64 + lane;
    const int cA1 = cA + 256;

    for (int k0 = 0; k0 < K; k0 += 32) {
        if (k0) __syncthreads();
        gl_lds16(A + (size_t)(m0 + (cA  >> 2)) * K + k0 + (cA  & 3) * 8,
                 &As[wave * 512]);
        gl_lds16(A + (size_t)(m0 + (cA1 >> 2)) * K + k0 + (cA1 & 3) * 8,
                 &As[2048 + wave * 512]);
        gl_lds16(BT + (size_t)(n0 + (cA  >> 2)) * K + k0 + (cA  & 3) * 8,
                 &Bs[wave * 512]);
        gl_lds16(BT + (size_t)(n0 + (cA1 >> 2)) * K + k0 + (cA1 & 3) * 8,
                 &Bs[2048 + wave * 512]);
        __syncthreads();

        bf16x8 af[4], bfr[4];
#pragma unroll
        for (int mt = 0; mt < 4; ++mt)
            af[mt] = *(const bf16x8*)&As[(mq + mt * 16 + col) * 32 + quad * 8];
#pragma unroll
        for (int nt = 0; nt < 4; ++nt)
            bfr[nt] = *(const bf16x8*)&Bs[(nq + nt * 16 + col) * 32 + quad * 8];
#pragma unroll
        for (int mt = 0; mt < 4; ++mt)
#pragma unroll
            for (int nt = 0; nt < 4; ++nt)
                acc[mt][nt] = __builtin_amdgcn_mfma_f32_16x16x32_bf16(
                    af[mt], bfr[nt], acc[mt][nt], 0, 0, 0);
    }

    if (FUSE_VT && n0 >= 2 * NEMBD) {
        // V^T epilogue: vt[(b*1024 + hd)][t], hd = col index - 2048, t = row.
#pragma unroll
        for (int mt = 0; mt < 4; ++mt) {
            const int row = m0 + mq + mt * 16 + quad * 4;   // +r consecutive
            const int bb  = row >> 11;                      // row / SEQ
            const int t   = row & (SEQ - 1);
#pragma unroll
            for (int nt = 0; nt < 4; ++nt) {
                const int hd = n0 + nq + nt * 16 + col - 2 * NEMBD;
                short* vp = vt + ((size_t)(bb * NEMBD + hd)) * SEQ + t;
                bf16x4 v;
                v[0] = f2bf(acc[mt][nt][0]);
                v[1] = f2bf(acc[mt][nt][1]);
                v[2] = f2bf(acc[mt][nt][2]);
                v[3] = f2bf(acc[mt][nt][3]);
                *(bf16x4*)vp = v;
            }
        }
        return;   // V columns of C are never read — skip the C store
    }

#pragma unroll
    for (int mt = 0; mt < 4; ++mt)
#pragma unroll
        for (int r = 0; r < 4; ++r) {
            const int row = m0 + mq + mt * 16 + quad * 4 + r;
            OT* cp = C + (size_t)row * N + n0 + nq + col;
#pragma unroll
            for (int nt = 0; nt < 4; ++nt)
                stc(cp + nt * 16, acc[mt][nt][r]);
        }
}

// ---------------------------------------------------------------------------
// MFMA flash attention v8: seg size 16 -> 8 (<=4 segs/slot), NO atomics.
// R10 post-mortem: only ~170 blocks carry 16-tile chains (< 256 CUs) -> each
// runs alone; makespan ~ 16*L_solo. Halving the chain is the only lever.
// Partial pools (fp32, unique slots):
//   segs 0/1: slots with T>8  (h>=9, X>=8: 336 slots) -> overlay (dead xb/wqt)
//   segs 2/3: slots with T>16 (h>=11,X>=16: 160 slots) -> d_out second half
// Single-seg slots (T<=8) write bf16 attnb directly. attn_merge sums <=4.
// Grid (hb, seg, Xi): hb fastest, X=31-Xi slowest-desc (global heavy-first).
// ---------------------------------------------------------------------------
__global__ __launch_bounds__(256) void attn_mfma(const short* __restrict__ qkvb,
                                                 const short* __restrict__ vt,
                                                 short* __restrict__ attnb,
                                                 float* __restrict__ partO01,
                                                 float* __restrict__ partO23,
                                                 float* __restrict__ partl) {
    // [buf][region][64 rows * 32 shorts]; regions: 0=Klo 1=Khi 2=Vlo 3=Vhi
    __shared__ short KV[2][4][2048];     // 32 KB
    __shared__ short P_lds[4][16 * 64];  // 8 KB -> total 40 KB = 4 blocks/CU

    const int tid  = threadIdx.x;
    const int wave = tid >> 6;
    const int lane = tid & 63;
    const int quad = lane >> 4;
    const int col  = lane & 15;

    const int hb  = blockIdx.x;              // fastest -> spreads heads
    const int seg = blockIdx.y;              // 0..3, 8 tiles each
    const int X   = 31 - (int)blockIdx.z;    // slowest, desc: global heavy-first
    const int h   = hb >> 1;
    const int b   = hb & 1;

    const float LOG2E  = 1.4426950408889634f;
    const float scale2 = 0.125f * LOG2E;
    const float slope2 = exp2f(-0.5f * (float)(h + 1)) * LOG2E;

    const int Tneed = X + 1;
    const int Tcut  = ((int)(ALIBI_MARGIN / slope2) >> 6) + 1;  // ALiBi truncation
    const int T     = Tneed < Tcut ? Tneed : Tcut;
    const int t0    = seg * 8;
    if (t0 >= T) return;                     // uniform early exit, before barriers
    const int tend  = min(t0 + 8, T);
    const bool sole = (T <= 8);              // single segment covers the slot

    const int q0 = X * 64 + wave * 16;

    const short* kb  = qkvb + (size_t)(b * SEQ) * C3 + NEMBD + h * HDIM;
    const short* vtb = vt + (size_t)(b * NHEAD + h) * HDIM * SEQ;

    // Q A-fragments: rows q0+col, dims quad*8 (+0 / +32)
    const short* qbase = qkvb + (size_t)(b * SEQ + q0 + col) * C3 + h * HDIM;
    const bf16x8 qa0 = *(const bf16x8*)(qbase + quad * 8);
    const bf16x8 qa1 = *(const bf16x8*)(qbase + 32 + quad * 8);

    f32x4 O0 = {0,0,0,0}, O1 = {0,0,0,0}, O2 = {0,0,0,0}, O3 = {0,0,0,0};
    float lsum[4] = {0.f, 0.f, 0.f, 0.f};
    short* P = P_lds[wave];

#define STAGE(t_, buf_) do {                                                   \
        const int jj = (t_) * 64;                                              \
        const int row = tid >> 2, g8 = (tid & 3) * 8;                          \
        gl_lds16(kb  + (size_t)(jj + row) * C3 + g8,      &KV[buf_][0][wave * 512]); \
        gl_lds16(kb  + (size_t)(jj + row) * C3 + 32 + g8, &KV[buf_][1][wave * 512]); \
        gl_lds16(vtb + (size_t)row * SEQ + jj + g8,       &KV[buf_][2][wave * 512]); \
        gl_lds16(vtb + (size_t)row * SEQ + jj + 32 + g8,  &KV[buf_][3][wave * 512]); \
    } while (0)

    STAGE(t0, 0);

    for (int t = t0; t < tend; ++t) {
        const int buf = (t - t0) & 1;
        __syncthreads();            // drains vmcnt -> buf ready; prev reads done
        if (t + 1 < tend) STAGE(t + 1, buf ^ 1);

        const int j0 = t * 64;

        // S = Q @ K^T from LDS K
        f32x4 S[4];
#pragma unroll
        for (int g = 0; g < 4; ++g) {
            bf16x8 k0 = *(const bf16x8*)&KV[buf][0][(g * 16 + col) * 32 + quad * 8];
            bf16x8 k1 = *(const bf16x8*)&KV[buf][1][(g * 16 + col) * 32 + quad * 8];
            f32x4 s = {0, 0, 0, 0};
            s = __builtin_amdgcn_mfma_f32_16x16x32_bf16(qa0, k0, s, 0, 0, 0);
            s = __builtin_amdgcn_mfma_f32_16x16x32_bf16(qa1, k1, s, 0, 0, 0);
            S[g] = s;
        }

        // softmax weights p = exp2(S*scale2 - slope2*j)
        const float cbase = -slope2 * (float)(j0 + col);
        const float d16   = -slope2 * 16.0f;
        float p[4][4];
        if (t == X) {               // diagonal tile: causal mask
#pragma unroll
            for (int g = 0; g < 4; ++g) {
                const float cg = cbase + d16 * (float)g;
                const int   jg = j0 + g * 16 + col;
#pragma unroll
                for (int r = 0; r < 4; ++r) {
                    const int i = q0 + quad * 4 + r;
                    p[g][r] = (jg <= i) ? exp2f(S[g][r] * scale2 + cg) : 0.f;
                }
            }
        } else {
#pragma unroll
            for (int g = 0; g < 4; ++g) {
                const float cg = cbase + d16 * (float)g;
#pragma unroll
                for (int r = 0; r < 4; ++r)
                    p[g][r] = exp2f(S[g][r] * scale2 + cg);
            }
        }
#pragma unroll
        for (int r = 0; r < 4; ++r)
            lsum[r] += (p[0][r] + p[1][r]) + (p[2][r] + p[3][r]);

        // P (C-layout) -> LDS [q][k] with rotation swizzle:
        // phys col = (k + (row>>2)*16) & 63; row>>2 == quad for the writer.
#pragma unroll
        for (int g = 0; g < 4; ++g)
#pragma unroll
            for (int r = 0; r < 4; ++r)
                P[(quad * 4 + r) * 64 + ((g * 16 + col + quad * 16) & 63)] = f2bf(p[g][r]);
        __asm__ volatile("s_waitcnt lgkmcnt(0)" ::: "memory");
        // reader of logical row q=col: rotation = (col>>2)*16
        const int rot = (col >> 2) * 16;
        bf16x8 pa0 = *(bf16x8*)&P[col * 64 + ((quad * 8 + rot) & 63)];
        bf16x8 pa1 = *(bf16x8*)&P[col * 64 + ((quad * 8 + 32 + rot) & 63)];
        __asm__ volatile("" ::: "memory");

        // O += P @ V: V^T B-fragments from LDS
        {
            bf16x8 vl0 = *(const bf16x8*)&KV[buf][2][(0 * 16 + col) * 32 + quad * 8];
            bf16x8 vh0 = *(const bf16x8*)&KV[buf][3][(0 * 16 + col) * 32 + quad * 8];
            O0 = __builtin_amdgcn_mfma_f32_16x16x32_bf16(pa0, vl0, O0, 0, 0, 0);
            O0 = __builtin_amdgcn_mfma_f32_16x16x32_bf16(pa1, vh0, O0, 0, 0, 0);
            bf16x8 vl1 = *(const bf16x8*)&KV[buf][2][(1 * 16 + col) * 32 + quad * 8];
            bf16x8 vh1 = *(const bf16x8*)&KV[buf][3][(1 * 16 + col) * 32 + quad * 8];
            O1 = __builtin_amdgcn_mfma_f32_16x16x32_bf16(pa0, vl1, O1, 0, 0, 0);
            O1 = __builtin_amdgcn_mfma_f32_16x16x32_bf16(pa1, vh1, O1, 0, 0, 0);
            bf16x8 vl2 = *(const bf16x8*)&KV[buf][2][(2 * 16 + col) * 32 + quad * 8];
            bf16x8 vh2 = *(const bf16x8*)&KV[buf][3][(2 * 16 + col) * 32 + quad * 8];
            O2 = __builtin_amdgcn_mfma_f32_16x16x32_bf16(pa0, vl2, O2, 0, 0, 0);
            O2 = __builtin_amdgcn_mfma_f32_16x16x32_bf16(pa1, vh2, O2, 0, 0, 0);
            bf16x8 vl3 = *(const bf16x8*)&KV[buf][2][(3 * 16 + col) * 32 + quad * 8];
            bf16x8 vh3 = *(const bf16x8*)&KV[buf][3][(3 * 16 + col) * 32 + quad * 8];
            O3 = __builtin_amdgcn_mfma_f32_16x16x32_bf16(pa0, vl3, O3, 0, 0, 0);
            O3 = __builtin_amdgcn_mfma_f32_16x16x32_bf16(pa1, vh3, O3, 0, 0, 0);
        }
    }
#undef STAGE

    // reduce l across the 16 key-columns
#pragma unroll
    for (int off = 1; off < 16; off <<= 1)
#pragma unroll
        for (int r = 0; r < 4; ++r)
            lsum[r] += __shfl_xor(lsum[r], off);

    if (sole) {
        // normalize + write bf16 attnb directly
#pragma unroll
        for (int r = 0; r < 4; ++r) {
            const float inv = 1.f / lsum[r];
            const int row = q0 + quad * 4 + r;
            short* op = attnb + (size_t)(b * SEQ + row) * NEMBD + h * HDIM;
            op[col]      = f2bf(O0[r] * inv);
            op[16 + col] = f2bf(O1[r] * inv);
            op[32 + col] = f2bf(O2[r] * inv);
            op[48 + col] = f2bf(O3[r] * inv);
        }
    } else {
        // T>8 here => h>=9 (Tcut>8) and X>=8; seg>=2 real => h>=11, X>=16.
        const int p01 = ((h - 9) * 2 + b) * 24 + (X - 8);      // 0..335
        float* pl = partl + ((size_t)p01 * 4 + seg) * 64 + wave * 16;
        float* pO;
        if (seg < 2) {
            pO = partO01 + ((size_t)p01 * 2 + seg) * 4096 + (size_t)(wave * 16) * 64;
        } else {
            const int p23 = ((h - 11) * 2 + b) * 16 + (X - 16);  // 0..159
            pO = partO23 + ((size_t)p23 * 2 + (seg - 2)) * 4096 + (size_t)(wave * 16) * 64;
        }
#pragma unroll
        for (int r = 0; r < 4; ++r) {
            float* rp = pO + (quad * 4 + r) * 64;
            rp[col]      = O0[r];
            rp[16 + col] = O1[r];
            rp[32 + col] = O2[r];
            rp[48 + col] = O3[r];
            if (col == 0) pl[quad * 4 + r] = lsum[r];
        }
    }
}

// ---------------------------------------------------------------------------
// Merge <=4 partial segments of split slots, normalize, write bf16 attnb.
// Grid 336 = p01 slots; slots with T<=8 never enter the pool (no such block).
// ---------------------------------------------------------------------------
__global__ __launch_bounds__(256) void attn_merge(const float* __restrict__ partO01,
                                                  const float* __restrict__ partO23,
                                                  const float* __restrict__ partl,
                                                  short* __restrict__ attnb) {
    const int p01 = blockIdx.x;
    const int g   = p01 / 24;
    const int X   = 8 + (p01 % 24);
    const int h   = 9 + (g >> 1);
    const int b   = g & 1;

    const float LOG2E  = 1.4426950408889634f;
    const float slope2 = exp2f(-0.5f * (float)(h + 1)) * LOG2E;
    const int Tcut = ((int)(ALIBI_MARGIN / slope2) >> 6) + 1;
    const int T = min(X + 1, Tcut);
    if (T <= 8) return;                       // slot was not split
    const int nseg = (T + 7) >> 3;            // 2..4

    const int q  = threadIdx.x >> 2;          // 0..63
    const int d0 = (threadIdx.x & 3) * 16;

    float l = 0.f;
    for (int s = 0; s < nseg; ++s)
        l += partl[((size_t)p01 * 4 + s) * 64 + q];
    const float inv = 1.f / l;

    float acc[16] = {};
    const int p23 = ((h - 11) * 2 + b) * 16 + (X - 16);   // valid iff nseg>2
    for (int s = 0; s < nseg; ++s) {
        const float* src = (s < 2)
            ? partO01 + ((size_t)p01 * 2 + s) * 4096 + q * 64 + d0
            : partO23 + ((size_t)p23 * 2 + (s - 2)) * 4096 + q * 64 + d0;
#pragma unroll
        for (int c = 0; c < 16; c += 4) {
            float4 v = *(const float4*)(src + c);
            acc[c] += v.x; acc[c + 1] += v.y; acc[c + 2] += v.z; acc[c + 3] += v.w;
        }
    }

    short* dst = attnb + (size_t)(b * SEQ + X * 64 + q) * NEMBD + h * HDIM + d0;
#pragma unroll
    for (int half = 0; half < 2; ++half) {
        bf16x8 o;
#pragma unroll
        for (int k = 0; k < 8; ++k) o[k] = f2bf(acc[half * 8 + k] * inv);
        *(bf16x8*)(dst + half * 8) = o;
    }
}

// ---------------------------------------------------------------------------
extern "C" void kernel_launch(void* const* d_in, const int* in_sizes, int n_in,
                              void* d_out, int out_size, void* d_ws, size_t ws_size,
                              hipStream_t stream) {
    const float* x      = (const float*)d_in[0];
    const float* w_qkv  = (const float*)d_in[1];
    const float* w_proj = (const float*)d_in[2];
    float* out = (float*)d_out;

    // ws: [xb 8.39 | wqt 6.29 | pad -> 16.78][qkvb 25.17][attnb 8.39][wpt 2.10]
    // After qkv GEMM, xb/wqt dead: partO01 (11.0 MB) + partl (0.34 MB) overlay.
    // d_out: [vt 8.39 (written by fused gemm epilogue)][partO23 5.25 | free]
    char*  base  = (char*)d_ws;
    short* xb    = (short*)base;
    short* wqt   = xb + (size_t)MROWS * NEMBD;
    float* partO01 = (float*)base;                               // 11.0 MB
    float* partl   = (float*)(base + (size_t)336 * 2 * 4096 * 4);// @11.0 MB, 344 KB
    short* qkvb  = (short*)(base + (size_t)1024 * 4096 * 4);     // @16.78 MB
    short* attnb = qkvb + (size_t)MROWS * C3;                    // @41.94 MB
    short* wpt   = attnb + (size_t)MROWS * NEMBD;                // @50.33 MB
    short* vt    = (short*)d_out;                                // 8.39 MB
    float* partO23 = (float*)((short*)d_out + (size_t)MROWS * NEMBD);  // 5.25 MB

    conv_all<<<dim3(3072), 256, 0, stream>>>(x, w_qkv, w_proj, xb, wqt, wpt);
    // qkv GEMM with fused V^T epilogue (V columns go to vt, not qkvb)
    gemm_bt<short, true><<<dim3(C3 / 128, MROWS / 128), 256, 0, stream>>>(
        xb, wqt, qkvb, MROWS, C3, NEMBD, vt);
    attn_mfma<<<dim3(32, 4, 32), 256, 0, stream>>>(qkvb, vt, attnb,
                                                   partO01, partO23, partl);
    attn_merge<<<dim3(336), 256, 0, stream>>>(partO01, partO23, partl, attnb);
    gemm_bt<float, false><<<dim3(NEMBD / 128, MROWS / 128), 256, 0, stream>>>(
        attnb, wpt, out, MROWS, NEMBD, NEMBD, nullptr);
}